// Round 6
// baseline (204.268 us; speedup 1.0000x reference)
//
#include <hip/hip_runtime.h>
#include <hip/hip_bf16.h>

#define T 128
#define C 20
#define KQ 100
#define NT 512
#define SCALE 0.08838834764831845f   // 1/sqrt(128)
#define LDP 136   // kp row stride (shorts): 272B, 16B-aligned, 2-way banks (free)
#define LDQ 120   // q row stride: 240B, 16B-aligned, 2-way banks
#define LDV 136   // vT row stride

typedef float  f32x4  __attribute__((ext_vector_type(4)));
typedef short  bf16x8 __attribute__((ext_vector_type(8)));
typedef unsigned int uint32;

__device__ __forceinline__ short f2bf(float f) {
    unsigned u = __builtin_bit_cast(unsigned, f);
    unsigned r = (u + 0x7FFFu + ((u >> 16) & 1u)) >> 16;   // RNE
    return (short)r;
}
__device__ __forceinline__ uint32 pk2(float a, float b) {  // v_cvt_pk_bf16_f32
    __hip_bfloat162 h = __float22bfloat162_rn(float2{a, b});
    uint32 r;
    __builtin_memcpy(&r, &h, 4);                           // plain reg move
    return r;
}

// ---- prep: weights -> bf16 A-fragment tiles in d_ws ----
// wAll = 16 tiles x [16 rows][32 k] bf16 (k:0..6, q:7..13, v:14..15), pads zero.
// bAll = 16 tiles x [16] f32 biases (pads zero).
__global__ void prep(const float* __restrict__ Wk, const float* __restrict__ bk,
                     const float* __restrict__ Wq, const float* __restrict__ bq,
                     const float* __restrict__ Wv, const float* __restrict__ bv,
                     short* __restrict__ wkT, short* __restrict__ wqT,
                     short* __restrict__ wvT, float* __restrict__ bkp,
                     float* __restrict__ bqp, float* __restrict__ bvp)
{
    const int t = blockIdx.x * blockDim.x + threadIdx.x;
    if (t < 112 * 32) {
        const int n = t >> 5, c = t & 31;
        const bool ok = (n < KQ) && (c < C);
        wkT[t] = f2bf(ok ? Wk[c * KQ + n] : 0.f);
        wqT[t] = f2bf(ok ? Wq[c * KQ + n] : 0.f);
        if (t < 32 * 32) {
            const int n2 = t >> 5, c2 = t & 31;
            wvT[t] = f2bf((n2 < C && c2 < C) ? Wv[c2 * C + n2] : 0.f);
        }
        if (t < 112) { bkp[t] = t < KQ ? bk[t] : 0.f; bqp[t] = t < KQ ? bq[t] : 0.f; }
        if (t < 32)  bvp[t] = t < C ? bv[t] : 0.f;
    }
}

// One block per batch, 512 threads, 72.5 KB LDS -> 2 blocks/CU.
// Everything on MFMA with SWAPPED operands so each thread's C/D values are
// row-contiguous: k/q/P epilogues use packed ds_write_b64; softmax is a pure
// in-register butterfly (no LDS atomics, 3 barriers total).
__global__ __launch_bounds__(NT, 4) void sa_fused(
    const float* __restrict__ x,
    const short* __restrict__ wAll, const float* __restrict__ bAll,
    float* __restrict__ y)
{
    __shared__ __align__(16) short kp_lds[T * LDP];   // k [i][d<=111] -> later P [i][j 0..127]
    __shared__ __align__(16) short q_lds [T * LDQ];   // q [j][d<=111]
    __shared__ __align__(16) short vT_lds[32 * LDV];  // v^T [dd][j] (rows 20..31 = tanh(0) = 0)

    const int tid  = threadIdx.x;
    const int lane = tid & 63;
    const int w    = __builtin_amdgcn_readfirstlane(tid >> 6);
    const int quad = lane >> 4;
    const int l16  = lane & 15;
    const int b    = blockIdx.x;
    const float* xb = x + (size_t)b * (T * C);

    // ---- x B-fragments, one per i-tile: B[k=c(quad*8+u)][n=i(l16)], c pad 20->32 ----
    bf16x8 xf[8];
    #pragma unroll
    for (int nt = 0; nt < 8; ++nt) {
        const float* xr = xb + (nt * 16 + l16) * C;
        uint32 p0 = 0, p1 = 0, p2 = 0, p3 = 0;
        if (quad < 2) {
            const float4 f0 = *(const float4*)(xr + quad * 8);
            const float4 f1 = *(const float4*)(xr + quad * 8 + 4);
            p0 = pk2(f0.x, f0.y); p1 = pk2(f0.z, f0.w);
            p2 = pk2(f1.x, f1.y); p3 = pk2(f1.z, f1.w);
        } else if (quad == 2) {
            const float4 f0 = *(const float4*)(xr + 16);
            p0 = pk2(f0.x, f0.y); p1 = pk2(f0.z, f0.w);
        }
        uint4 u4; u4.x = p0; u4.y = p1; u4.z = p2; u4.w = p3;
        xf[nt] = __builtin_bit_cast(bf16x8, u4);
    }

    // ---- projections: wave w owns output-tiles {2w, 2w+1} of [k(7)|q(7)|v(2)] ----
    // C/D: row = out-channel = tile*16+quad*4+r (contiguous per thread), col = i = l16.
    #pragma unroll
    for (int s = 0; s < 2; ++s) {
        const int tt = 2 * w + s;                                 // wave-uniform
        const bf16x8 wa = *(const bf16x8*)(wAll + (tt * 16 + l16) * 32 + quad * 8);
        const float4 bb4 = *(const float4*)(bAll + tt * 16 + quad * 4);
        const float bbv[4] = {bb4.x, bb4.y, bb4.z, bb4.w};
        #pragma unroll
        for (int nt = 0; nt < 8; ++nt) {
            const f32x4 cc = __builtin_amdgcn_mfma_f32_16x16x32_bf16(
                wa, xf[nt], (f32x4){0.f, 0.f, 0.f, 0.f}, 0, 0, 0);
            if (tt < 14) {                                        // k or q: ELU
                float e[4];
                #pragma unroll
                for (int r = 0; r < 4; ++r) {
                    const float z = cc[r] + bbv[r];
                    e[r] = z > 0.f ? z : (__expf(z) - 1.f);
                }
                short* dst = (tt < 7)
                    ? &kp_lds[(nt * 16 + l16) * LDP + tt * 16 + quad * 4]
                    : &q_lds [(nt * 16 + l16) * LDQ + (tt - 7) * 16 + quad * 4];
                uint2 pk; pk.x = pk2(e[0], e[1]); pk.y = pk2(e[2], e[3]);
                *(uint2*)dst = pk;                                // ds_write_b64
            } else {                                              // v: tanh -> vT (scattered, 1 wave)
                #pragma unroll
                for (int r = 0; r < 4; ++r) {
                    const float z = cc[r] + bbv[r];
                    const float e2 = __expf(2.f * z);
                    vT_lds[((tt - 14) * 16 + quad * 4 + r) * LDV + nt * 16 + l16]
                        = f2bf(1.f - 2.f / (e2 + 1.f));
                }
            }
        }
    }
    __syncthreads();

    // ---- scores TRANSPOSED: S^T = q·k^T. A = q rows j (m-tile w), B = k (n = i). ----
    f32x4 acc[8];
    #pragma unroll
    for (int nt = 0; nt < 8; ++nt) acc[nt] = (f32x4){0.f, 0.f, 0.f, 0.f};
    #pragma unroll
    for (int ks = 0; ks < 4; ++ks) {
        bf16x8 a = {0, 0, 0, 0, 0, 0, 0, 0};
        if (ks < 3 || quad < 2)
            a = *(const bf16x8*)&q_lds[(w * 16 + l16) * LDQ + ks * 32 + quad * 8];
        #pragma unroll
        for (int nt = 0; nt < 8; ++nt) {
            bf16x8 bk8 = {0, 0, 0, 0, 0, 0, 0, 0};
            if (ks < 3 || quad < 2)
                bk8 = *(const bf16x8*)&kp_lds[(nt * 16 + l16) * LDP + ks * 32 + quad * 8];
            acc[nt] = __builtin_amdgcn_mfma_f32_16x16x32_bf16(a, bk8, acc[nt], 0, 0, 0);
        }
    }

    // ---- softmax over i (axis=1), fully in registers ----
    // Thread holds (j = w*16+quad*4+r, i = nt*16+l16). Sum over i = nt-sum + l16 butterfly.
    float ssum[4] = {0.f, 0.f, 0.f, 0.f};
    #pragma unroll
    for (int nt = 0; nt < 8; ++nt)
        #pragma unroll
        for (int r = 0; r < 4; ++r) {
            const float e = __expf(acc[nt][r] * SCALE);
            acc[nt][r] = e;
            ssum[r] += e;
        }
    #pragma unroll
    for (int r = 0; r < 4; ++r) {
        float s = ssum[r];
        s += __shfl_xor(s, 1); s += __shfl_xor(s, 2);
        s += __shfl_xor(s, 4); s += __shfl_xor(s, 8);
        ssum[r] = 1.f / s;                                        // linv[j], all lanes
    }
    __syncthreads();                                              // score reads of kp done

    // ---- write P[i][j] (b64-packed: 4 consecutive j per thread) over k ----
    #pragma unroll
    for (int nt = 0; nt < 8; ++nt) {
        uint2 pk;
        pk.x = pk2(acc[nt][0] * ssum[0], acc[nt][1] * ssum[1]);
        pk.y = pk2(acc[nt][2] * ssum[2], acc[nt][3] * ssum[3]);
        *(uint2*)&kp_lds[(nt * 16 + l16) * LDP + w * 16 + quad * 4] = pk;
    }
    __syncthreads();

    // ---- PV: A = P (m-tile w, K = j = 128), B = v^T (N = 32) ----
    f32x4 yacc[2];
    yacc[0] = (f32x4){0.f, 0.f, 0.f, 0.f};
    yacc[1] = (f32x4){0.f, 0.f, 0.f, 0.f};
    #pragma unroll
    for (int ks = 0; ks < 4; ++ks) {
        const bf16x8 a = *(const bf16x8*)&kp_lds[(w * 16 + l16) * LDP + ks * 32 + quad * 8];
        #pragma unroll
        for (int nt = 0; nt < 2; ++nt) {
            const bf16x8 bv8 = *(const bf16x8*)&vT_lds[(nt * 16 + l16) * LDV + ks * 32 + quad * 8];
            yacc[nt] = __builtin_amdgcn_mfma_f32_16x16x32_bf16(a, bv8, yacc[nt], 0, 0, 0);
        }
    }

    // ---- epilogue: y = PV + x ----
    {
        float* yb = y + (size_t)b * (T * C);
        #pragma unroll
        for (int r = 0; r < 4; ++r) {
            const int row  = w * 16 + quad * 4 + r;
            const int base = row * C;
            yb[base + l16] = yacc[0][r] + xb[base + l16];
            if (l16 < 4)
                yb[base + 16 + l16] = yacc[1][r] + xb[base + 16 + l16];
        }
    }
}

extern "C" void kernel_launch(void* const* d_in, const int* in_sizes, int n_in,
                              void* d_out, int out_size, void* d_ws, size_t ws_size,
                              hipStream_t stream) {
    const float* x  = (const float*)d_in[0];
    const float* Wk = (const float*)d_in[1];
    const float* bk = (const float*)d_in[2];
    const float* Wq = (const float*)d_in[3];
    const float* bq = (const float*)d_in[4];
    const float* Wv = (const float*)d_in[5];
    const float* bv = (const float*)d_in[6];
    float* y = (float*)d_out;

    char* ws = (char*)d_ws;
    short* wkT = (short*)ws;                 // tiles 0..6   [112][32] bf16
    short* wqT = (short*)(ws + 7168);        // tiles 7..13  [112][32] bf16
    short* wvT = (short*)(ws + 14336);       // tiles 14..15 [32][32] bf16
    float* bkp = (float*)(ws + 16384);       // [112]
    float* bqp = (float*)(ws + 16832);       // [112]
    float* bvp = (float*)(ws + 17280);       // [32]

    prep<<<14, 256, 0, stream>>>(Wk, bk, Wq, bq, Wv, bv, wkT, wqT, wvT, bkp, bqp, bvp);

    const int B = in_sizes[0] / (T * C);     // 4096
    sa_fused<<<B, NT, 0, stream>>>(x, (const short*)ws, (const float*)(ws + 16384), y);
}

// Round 7
// 173.433 us; speedup vs baseline: 1.1778x; 1.1778x over previous
//
#include <hip/hip_runtime.h>
#include <hip/hip_bf16.h>

#define T 128
#define C 20
#define KQ 100
#define NT 512
#define SCALE 0.08838834764831845f   // 1/sqrt(128)
#define LDP 136   // kp row stride (shorts): 272B, 16B-aligned; cols 112..135 zeroed
#define LDQ 136   // q row stride: cols 112..135 zeroed (unpredicated K-loop)
#define LDV 136   // vT row stride

typedef float  f32x4  __attribute__((ext_vector_type(4)));
typedef short  bf16x8 __attribute__((ext_vector_type(8)));
typedef unsigned int uint32;

__device__ __forceinline__ short f2bf(float f) {
    unsigned u = __builtin_bit_cast(unsigned, f);
    unsigned r = (u + 0x7FFFu + ((u >> 16) & 1u)) >> 16;   // RNE
    return (short)r;
}
__device__ __forceinline__ uint32 pk2(float a, float b) {  // v_cvt_pk_bf16_f32
    __hip_bfloat162 h = __float22bfloat162_rn(float2{a, b});
    uint32 r;
    __builtin_memcpy(&r, &h, 4);
    return r;
}

// ---- prep: weights -> bf16 A-fragment tiles in d_ws ----
// wAll = 16 tiles x [16 ch][32 c] bf16 (k:0..6, q:7..13, v:14..15), pads zero.
// bAll = 16 tiles x [16] f32 biases (pads zero).
__global__ void prep(const float* __restrict__ Wk, const float* __restrict__ bk,
                     const float* __restrict__ Wq, const float* __restrict__ bq,
                     const float* __restrict__ Wv, const float* __restrict__ bv,
                     short* __restrict__ wkT, short* __restrict__ wqT,
                     short* __restrict__ wvT, float* __restrict__ bkp,
                     float* __restrict__ bqp, float* __restrict__ bvp)
{
    const int t = blockIdx.x * blockDim.x + threadIdx.x;
    if (t < 112 * 32) {
        const int n = t >> 5, c = t & 31;
        const bool ok = (n < KQ) && (c < C);
        wkT[t] = f2bf(ok ? Wk[c * KQ + n] : 0.f);
        wqT[t] = f2bf(ok ? Wq[c * KQ + n] : 0.f);
        if (t < 32 * 32) {
            const int n2 = t >> 5, c2 = t & 31;
            wvT[t] = f2bf((n2 < C && c2 < C) ? Wv[c2 * C + n2] : 0.f);
        }
        if (t < 112) { bkp[t] = t < KQ ? bk[t] : 0.f; bqp[t] = t < KQ ? bq[t] : 0.f; }
        if (t < 32)  bvp[t] = t < C ? bv[t] : 0.f;
    }
}

// One block per batch, 512 threads, 78.3 KB LDS -> 2 blocks/CU.
// Projections: wave w owns i-tile w; B = x frag (built once), A = 16 weight
// frags streamed from L1-hot global. k/q/P epilogues are packed ds_write_b64;
// softmax is a pure in-register butterfly; 3 barriers total.
__global__ __launch_bounds__(NT, 4) void sa_fused(
    const float* __restrict__ x,
    const short* __restrict__ wAll, const float* __restrict__ bAll,
    float* __restrict__ y)
{
    __shared__ __align__(16) short kp_lds[T * LDP];   // k [i][d] -> later P [i][j]
    __shared__ __align__(16) short q_lds [T * LDQ];   // q [j][d]
    __shared__ __align__(16) short vT_lds[32 * LDV];  // v^T [dd][pos] (rows 20..31 = 0)

    const int tid  = threadIdx.x;
    const int lane = tid & 63;
    const int w    = __builtin_amdgcn_readfirstlane(tid >> 6);
    const int quad = lane >> 4;
    const int l16  = lane & 15;
    const int b    = blockIdx.x;
    const float* xb = x + (size_t)b * (T * C);

    // ---- zero k/q pad cols 112..135 (3 x uint4 per row per buffer) ----
    {
        const uint4 z = {0u, 0u, 0u, 0u};
        for (int idx = tid; idx < T * 3; idx += NT) {
            const int row = idx / 3, seg = idx % 3;
            *(uint4*)&kp_lds[row * LDP + 112 + seg * 8] = z;
            *(uint4*)&q_lds [row * LDQ + 112 + seg * 8] = z;
        }
    }

    // ---- x fragment (built ONCE): per-lane layout A[m=l16][k=quad*8+u]
    //      == B[k=quad*8+u][n=l16]; covers i-tile w, c padded 20->32 ----
    bf16x8 xf;
    {
        const float* xr = xb + (w * 16 + l16) * C;
        uint32 p0 = 0, p1 = 0, p2 = 0, p3 = 0;
        if (quad < 2) {
            const float4 f0 = *(const float4*)(xr + quad * 8);
            const float4 f1 = *(const float4*)(xr + quad * 8 + 4);
            p0 = pk2(f0.x, f0.y); p1 = pk2(f0.z, f0.w);
            p2 = pk2(f1.x, f1.y); p3 = pk2(f1.z, f1.w);
        } else if (quad == 2) {
            const float4 f0 = *(const float4*)(xr + 16);
            p0 = pk2(f0.x, f0.y); p1 = pk2(f0.z, f0.w);
        }
        uint4 u4; u4.x = p0; u4.y = p1; u4.z = p2; u4.w = p3;
        xf = __builtin_bit_cast(bf16x8, u4);
    }

    // ---- projections: stream 16 weight A-frags; C/D row = channel (contig),
    //      col = i = l16 within i-tile w. k/q -> b64 writes; v -> vT scatter. ----
    #pragma unroll
    for (int tt = 0; tt < 16; ++tt) {
        const bf16x8 wa = *(const bf16x8*)(wAll + (tt * 16 + l16) * 32 + quad * 8);
        const float4 bb4 = *(const float4*)(bAll + tt * 16 + quad * 4);
        const float bbv[4] = {bb4.x, bb4.y, bb4.z, bb4.w};
        const f32x4 cc = __builtin_amdgcn_mfma_f32_16x16x32_bf16(
            wa, xf, (f32x4){0.f, 0.f, 0.f, 0.f}, 0, 0, 0);
        if (tt < 14) {                                            // k or q: ELU
            float e[4];
            #pragma unroll
            for (int r = 0; r < 4; ++r) {
                const float z = cc[r] + bbv[r];
                e[r] = z > 0.f ? z : (__expf(z) - 1.f);
            }
            short* dst = (tt < 7)
                ? &kp_lds[(w * 16 + l16) * LDP + tt * 16 + quad * 4]
                : &q_lds [(w * 16 + l16) * LDQ + (tt - 7) * 16 + quad * 4];
            uint2 pk; pk.x = pk2(e[0], e[1]); pk.y = pk2(e[2], e[3]);
            *(uint2*)dst = pk;                                    // ds_write_b64
        } else {                                                  // v: tanh -> vT[dd][pos]
            #pragma unroll
            for (int r = 0; r < 4; ++r) {
                const float z = cc[r] + bbv[r];
                const float e2 = __expf(2.f * z);
                vT_lds[((tt - 14) * 16 + quad * 4 + r) * LDV + w * 16 + l16]
                    = f2bf(1.f - 2.f / (e2 + 1.f));
            }
        }
    }
    __syncthreads();

    // ---- scores TRANSPOSED: S^T = q·k^T. A = q rows j (m-tile w), B = k (n = i). ----
    // Unpredicated: cols 112..127 of both buffers are zeros.
    f32x4 acc[8];
    #pragma unroll
    for (int nt = 0; nt < 8; ++nt) acc[nt] = (f32x4){0.f, 0.f, 0.f, 0.f};
    #pragma unroll
    for (int ks = 0; ks < 4; ++ks) {
        const bf16x8 a = *(const bf16x8*)&q_lds[(w * 16 + l16) * LDQ + ks * 32 + quad * 8];
        #pragma unroll
        for (int nt = 0; nt < 8; ++nt) {
            const bf16x8 bk8 = *(const bf16x8*)&kp_lds[(nt * 16 + l16) * LDP + ks * 32 + quad * 8];
            acc[nt] = __builtin_amdgcn_mfma_f32_16x16x32_bf16(a, bk8, acc[nt], 0, 0, 0);
        }
    }

    // ---- softmax over i (axis=1), fully in registers ----
    // Thread holds (j = w*16+quad*4+r, i = nt*16+l16). Sum over i = nt-sum + l16 butterfly.
    float ssum[4] = {0.f, 0.f, 0.f, 0.f};
    #pragma unroll
    for (int nt = 0; nt < 8; ++nt)
        #pragma unroll
        for (int r = 0; r < 4; ++r) {
            const float e = __expf(acc[nt][r] * SCALE);
            acc[nt][r] = e;
            ssum[r] += e;
        }
    #pragma unroll
    for (int r = 0; r < 4; ++r) {
        float s = ssum[r];
        s += __shfl_xor(s, 1); s += __shfl_xor(s, 2);
        s += __shfl_xor(s, 4); s += __shfl_xor(s, 8);
        ssum[r] = 1.f / s;                                        // linv[j], all lanes
    }
    __syncthreads();                                              // score reads of kp done

    // ---- write P[i][j] (b64-packed: 4 consecutive j per thread) over k ----
    #pragma unroll
    for (int nt = 0; nt < 8; ++nt) {
        uint2 pk;
        pk.x = pk2(acc[nt][0] * ssum[0], acc[nt][1] * ssum[1]);
        pk.y = pk2(acc[nt][2] * ssum[2], acc[nt][3] * ssum[3]);
        *(uint2*)&kp_lds[(nt * 16 + l16) * LDP + w * 16 + quad * 4] = pk;
    }
    __syncthreads();

    // ---- PV: A = P (m-tile w, K = j = 128), B = v^T (N = 32) ----
    f32x4 yacc[2];
    yacc[0] = (f32x4){0.f, 0.f, 0.f, 0.f};
    yacc[1] = (f32x4){0.f, 0.f, 0.f, 0.f};
    #pragma unroll
    for (int ks = 0; ks < 4; ++ks) {
        const bf16x8 a = *(const bf16x8*)&kp_lds[(w * 16 + l16) * LDP + ks * 32 + quad * 8];
        #pragma unroll
        for (int nt = 0; nt < 2; ++nt) {
            const bf16x8 bv8 = *(const bf16x8*)&vT_lds[(nt * 16 + l16) * LDV + ks * 32 + quad * 8];
            yacc[nt] = __builtin_amdgcn_mfma_f32_16x16x32_bf16(a, bv8, yacc[nt], 0, 0, 0);
        }
    }

    // ---- epilogue: y = PV + x ----
    {
        float* yb = y + (size_t)b * (T * C);
        #pragma unroll
        for (int r = 0; r < 4; ++r) {
            const int row  = w * 16 + quad * 4 + r;
            const int base = row * C;
            yb[base + l16] = yacc[0][r] + xb[base + l16];
            if (l16 < 4)
                yb[base + 16 + l16] = yacc[1][r] + xb[base + 16 + l16];
        }
    }
}

extern "C" void kernel_launch(void* const* d_in, const int* in_sizes, int n_in,
                              void* d_out, int out_size, void* d_ws, size_t ws_size,
                              hipStream_t stream) {
    const float* x  = (const float*)d_in[0];
    const float* Wk = (const float*)d_in[1];
    const float* bk = (const float*)d_in[2];
    const float* Wq = (const float*)d_in[3];
    const float* bq = (const float*)d_in[4];
    const float* Wv = (const float*)d_in[5];
    const float* bv = (const float*)d_in[6];
    float* y = (float*)d_out;

    char* ws = (char*)d_ws;
    short* wkT = (short*)ws;                 // tiles 0..6   [112][32] bf16
    short* wqT = (short*)(ws + 7168);        // tiles 7..13  [112][32] bf16
    short* wvT = (short*)(ws + 14336);       // tiles 14..15 [32][32] bf16
    float* bkp = (float*)(ws + 16384);       // [112]
    float* bqp = (float*)(ws + 16832);       // [112]
    float* bvp = (float*)(ws + 17280);       // [32]

    prep<<<14, 256, 0, stream>>>(Wk, bk, Wq, bq, Wv, bv, wkT, wqT, wvT, bkp, bqp, bvp);

    const int B = in_sizes[0] / (T * C);     // 4096
    sa_fused<<<B, NT, 0, stream>>>(x, (const short*)ws, (const float*)(ws + 16384), y);
}

// Round 8
// 164.576 us; speedup vs baseline: 1.2412x; 1.0538x over previous
//
#include <hip/hip_runtime.h>
#include <hip/hip_bf16.h>

#define T 128
#define C 20
#define KQ 100
#define NT 512
#define SCALE 0.08838834764831845f   // 1/sqrt(128)
#define LDS8 136   // fp8 row stride (bytes): 34 dw == 2 mod 32 -> all accesses <=2-way (free)

typedef float  f32x4  __attribute__((ext_vector_type(4)));
typedef short  bf16x8 __attribute__((ext_vector_type(8)));
typedef unsigned int uint32;

__device__ __forceinline__ short f2bf(float f) {
    unsigned u = __builtin_bit_cast(unsigned, f);
    unsigned r = (u + 0x7FFFu + ((u >> 16) & 1u)) >> 16;   // RNE
    return (short)r;
}
__device__ __forceinline__ uint32 pk2(float a, float b) {  // v_cvt_pk_bf16_f32
    __hip_bfloat162 h = __float22bfloat162_rn(float2{a, b});
    uint32 r;
    __builtin_memcpy(&r, &h, 4);
    return r;
}
__device__ __forceinline__ int pkfp8x4(float a, float b, float c, float d) {
    int r = __builtin_amdgcn_cvt_pk_fp8_f32(a, b, 0, false);   // bytes 0,1
    r = __builtin_amdgcn_cvt_pk_fp8_f32(c, d, r, true);        // bytes 2,3
    return r;
}
__device__ __forceinline__ unsigned char fp8_1(float a) {
    return (unsigned char)(__builtin_amdgcn_cvt_pk_fp8_f32(a, 0.f, 0, false) & 0xff);
}

// ---- prep: weights -> bf16 A-fragment tiles in d_ws (unchanged layout) ----
// wAll = 16 tiles x [16 ch][32 c] bf16 (k:0..6, q:7..13, v:14..15), pads zero.
// bAll = 16 tiles x [16] f32 biases (pads zero).
__global__ void prep(const float* __restrict__ Wk, const float* __restrict__ bk,
                     const float* __restrict__ Wq, const float* __restrict__ bq,
                     const float* __restrict__ Wv, const float* __restrict__ bv,
                     short* __restrict__ wkT, short* __restrict__ wqT,
                     short* __restrict__ wvT, float* __restrict__ bkp,
                     float* __restrict__ bqp, float* __restrict__ bvp)
{
    const int t = blockIdx.x * blockDim.x + threadIdx.x;
    if (t < 112 * 32) {
        const int n = t >> 5, c = t & 31;
        const bool ok = (n < KQ) && (c < C);
        wkT[t] = f2bf(ok ? Wk[c * KQ + n] : 0.f);
        wqT[t] = f2bf(ok ? Wq[c * KQ + n] : 0.f);
        if (t < 32 * 32) {
            const int n2 = t >> 5, c2 = t & 31;
            wvT[t] = f2bf((n2 < C && c2 < C) ? Wv[c2 * C + n2] : 0.f);
        }
        if (t < 112) { bkp[t] = t < KQ ? bk[t] : 0.f; bqp[t] = t < KQ ? bq[t] : 0.f; }
        if (t < 32)  bvp[t] = t < C ? bv[t] : 0.f;
    }
}

// One block per batch, 512 threads, 38.3 KB LDS -> 4 blocks/CU (full occupancy).
// Projections on bf16 MFMA (bias folded into C operand); scores + PV on fp8
// e4m3 MFMA with b64 fragment reads. P stored as 64*P (avoids e4m3 subnormal
// zone), y scaled back by 1/64 in the epilogue. 3 barriers total.
__global__ __launch_bounds__(NT, 8) void sa_fused(
    const float* __restrict__ x,
    const short* __restrict__ wAll, const float* __restrict__ bAll,
    float* __restrict__ y)
{
    __shared__ __align__(16) unsigned char kp8[T * LDS8];   // k fp8 [i][d] -> later 64*P [i][j]
    __shared__ __align__(16) unsigned char q8 [T * LDS8];   // q fp8 [j][d]
    __shared__ __align__(16) unsigned char vT8[32 * LDS8];  // v^T fp8 [dd][pos] (rows 20..31 = 0)

    const int tid  = threadIdx.x;
    const int lane = tid & 63;
    const int w    = __builtin_amdgcn_readfirstlane(tid >> 6);
    const int quad = lane >> 4;
    const int l16  = lane & 15;
    const int b    = blockIdx.x;
    const float* xb = x + (size_t)b * (T * C);

    // ---- zero pad cols 112..127 of kp8/q8 (d-tail; read by score K-loop) ----
    if (tid < T) {
        const uint2 z = {0u, 0u};
        *(uint2*)&kp8[tid * LDS8 + 112] = z;
        *(uint2*)&kp8[tid * LDS8 + 120] = z;
        *(uint2*)&q8 [tid * LDS8 + 112] = z;
        *(uint2*)&q8 [tid * LDS8 + 120] = z;
    }

    // ---- x fragment (built once): A[m=l16][k=quad*8+u] == B[k][n=l16]; c pad 20->32 ----
    bf16x8 xf;
    {
        const float* xr = xb + (w * 16 + l16) * C;
        uint32 p0 = 0, p1 = 0, p2 = 0, p3 = 0;
        if (quad < 2) {
            const float4 f0 = *(const float4*)(xr + quad * 8);
            const float4 f1 = *(const float4*)(xr + quad * 8 + 4);
            p0 = pk2(f0.x, f0.y); p1 = pk2(f0.z, f0.w);
            p2 = pk2(f1.x, f1.y); p3 = pk2(f1.z, f1.w);
        } else if (quad == 2) {
            const float4 f0 = *(const float4*)(xr + 16);
            p0 = pk2(f0.x, f0.y); p1 = pk2(f0.z, f0.w);
        }
        uint4 u4; u4.x = p0; u4.y = p1; u4.z = p2; u4.w = p3;
        xf = __builtin_bit_cast(bf16x8, u4);
    }

    // ---- projections (bf16 MFMA, bias in C): wave w owns i-tile w ----
    // C/D: row = channel tt*16+quad*4+r (contiguous per thread), col = i = l16.
    #pragma unroll
    for (int tt = 0; tt < 16; ++tt) {
        const bf16x8 wa = *(const bf16x8*)(wAll + (tt * 16 + l16) * 32 + quad * 8);
        const float4 bb4 = *(const float4*)(bAll + tt * 16 + quad * 4);
        f32x4 cini; cini[0] = bb4.x; cini[1] = bb4.y; cini[2] = bb4.z; cini[3] = bb4.w;
        const f32x4 cc = __builtin_amdgcn_mfma_f32_16x16x32_bf16(wa, xf, cini, 0, 0, 0);
        if (tt < 14) {                                            // k or q: ELU -> fp8 b32 write
            float e[4];
            #pragma unroll
            for (int r = 0; r < 4; ++r) {
                const float z = cc[r];
                e[r] = z > 0.f ? z : (__expf(z) - 1.f);
            }
            unsigned char* dst = (tt < 7)
                ? &kp8[(w * 16 + l16) * LDS8 + tt * 16 + quad * 4]
                : &q8 [(w * 16 + l16) * LDS8 + (tt - 7) * 16 + quad * 4];
            *(int*)dst = pkfp8x4(e[0], e[1], e[2], e[3]);
        } else {                                                  // v: tanh -> vT scatter (b8)
            #pragma unroll
            for (int r = 0; r < 4; ++r) {
                const float e2 = __expf(2.f * cc[r]);
                vT8[((tt - 14) * 16 + quad * 4 + r) * LDS8 + w * 16 + l16]
                    = fp8_1(1.f - 2.f / (e2 + 1.f));
            }
        }
    }
    __syncthreads();

    // ---- scores TRANSPOSED (fp8): S^T = q.k^T. A = q rows j (m-tile w), B = k (n=i). ----
    f32x4 acc[8];
    #pragma unroll
    for (int nt = 0; nt < 8; ++nt) acc[nt] = (f32x4){0.f, 0.f, 0.f, 0.f};
    #pragma unroll
    for (int ks = 0; ks < 4; ++ks) {
        const long a = *(const long*)&q8[(w * 16 + l16) * LDS8 + ks * 32 + quad * 8];
        #pragma unroll
        for (int nt = 0; nt < 8; ++nt) {
            const long bk8 = *(const long*)&kp8[(nt * 16 + l16) * LDS8 + ks * 32 + quad * 8];
            acc[nt] = __builtin_amdgcn_mfma_f32_16x16x32_fp8_fp8(a, bk8, acc[nt], 0, 0, 0);
        }
    }

    // ---- softmax over i (axis=1), in registers ----
    // Thread holds (j = w*16+quad*4+r, i = nt*16+l16). Sum over i = nt-sum + l16 butterfly.
    float ssum[4] = {0.f, 0.f, 0.f, 0.f};
    #pragma unroll
    for (int nt = 0; nt < 8; ++nt)
        #pragma unroll
        for (int r = 0; r < 4; ++r) {
            const float e = __expf(acc[nt][r] * SCALE);
            acc[nt][r] = e;
            ssum[r] += e;
        }
    #pragma unroll
    for (int r = 0; r < 4; ++r) {
        float s = ssum[r];
        s += __shfl_xor(s, 1); s += __shfl_xor(s, 2);
        s += __shfl_xor(s, 4); s += __shfl_xor(s, 8);
        ssum[r] = 64.f / s;                                       // 64*linv[j] (fp8 range lift)
    }
    __syncthreads();                                              // all score reads of kp8 done

    // ---- write 64*P[i][j] fp8 (b32: 4 consecutive j per thread) over k ----
    #pragma unroll
    for (int nt = 0; nt < 8; ++nt) {
        *(int*)&kp8[(nt * 16 + l16) * LDS8 + w * 16 + quad * 4]
            = pkfp8x4(acc[nt][0] * ssum[0], acc[nt][1] * ssum[1],
                      acc[nt][2] * ssum[2], acc[nt][3] * ssum[3]);
    }
    __syncthreads();

    // ---- PV (fp8): A = 64P (m-tile w, K = j = 128), B = v^T (N = 32) ----
    f32x4 yacc[2];
    yacc[0] = (f32x4){0.f, 0.f, 0.f, 0.f};
    yacc[1] = (f32x4){0.f, 0.f, 0.f, 0.f};
    #pragma unroll
    for (int ks = 0; ks < 4; ++ks) {
        const long a = *(const long*)&kp8[(w * 16 + l16) * LDS8 + ks * 32 + quad * 8];
        #pragma unroll
        for (int nt = 0; nt < 2; ++nt) {
            const long bv8 = *(const long*)&vT8[(nt * 16 + l16) * LDS8 + ks * 32 + quad * 8];
            yacc[nt] = __builtin_amdgcn_mfma_f32_16x16x32_fp8_fp8(a, bv8, yacc[nt], 0, 0, 0);
        }
    }

    // ---- epilogue: y = PV/64 + x ----
    {
        float* yb = y + (size_t)b * (T * C);
        const float inv64 = 1.f / 64.f;
        #pragma unroll
        for (int r = 0; r < 4; ++r) {
            const int row  = w * 16 + quad * 4 + r;
            const int base = row * C;
            yb[base + l16] = yacc[0][r] * inv64 + xb[base + l16];
            if (l16 < 4)
                yb[base + 16 + l16] = yacc[1][r] * inv64 + xb[base + 16 + l16];
        }
    }
}

extern "C" void kernel_launch(void* const* d_in, const int* in_sizes, int n_in,
                              void* d_out, int out_size, void* d_ws, size_t ws_size,
                              hipStream_t stream) {
    const float* x  = (const float*)d_in[0];
    const float* Wk = (const float*)d_in[1];
    const float* bk = (const float*)d_in[2];
    const float* Wq = (const float*)d_in[3];
    const float* bq = (const float*)d_in[4];
    const float* Wv = (const float*)d_in[5];
    const float* bv = (const float*)d_in[6];
    float* y = (float*)d_out;

    char* ws = (char*)d_ws;
    short* wkT = (short*)ws;                 // tiles 0..6   [112][32] bf16
    short* wqT = (short*)(ws + 7168);        // tiles 7..13  [112][32] bf16
    short* wvT = (short*)(ws + 14336);       // tiles 14..15 [32][32] bf16
    float* bkp = (float*)(ws + 16384);       // [112]
    float* bqp = (float*)(ws + 16832);       // [112]
    float* bvp = (float*)(ws + 17280);       // [32]

    prep<<<14, 256, 0, stream>>>(Wk, bk, Wq, bq, Wv, bv, wkT, wqT, wvT, bkp, bqp, bvp);

    const int B = in_sizes[0] / (T * C);     // 4096
    sa_fused<<<B, NT, 0, stream>>>(x, (const short*)ws, (const float*)(ws + 16384), y);
}

// Round 10
// 158.587 us; speedup vs baseline: 1.2881x; 1.0378x over previous
//
#include <hip/hip_runtime.h>
#include <hip/hip_bf16.h>

#define T 128
#define C 20
#define KQ 100
#define NT 512
#define SCALE 0.08838834764831845f   // 1/sqrt(128)
#define LDS8 136   // fp8 row stride (bytes): 34 dw == 2 mod 32 -> all accesses <=2-way (free)

typedef float  f32x4  __attribute__((ext_vector_type(4)));
typedef short  bf16x8 __attribute__((ext_vector_type(8)));
typedef unsigned int uint32;

__device__ __forceinline__ short f2bf(float f) {
    unsigned u = __builtin_bit_cast(unsigned, f);
    unsigned r = (u + 0x7FFFu + ((u >> 16) & 1u)) >> 16;   // RNE
    return (short)r;
}
__device__ __forceinline__ uint32 pk2(float a, float b) {  // v_cvt_pk_bf16_f32
    __hip_bfloat162 h = __float22bfloat162_rn(float2{a, b});
    uint32 r;
    __builtin_memcpy(&r, &h, 4);
    return r;
}
__device__ __forceinline__ int pkfp8x4(float a, float b, float c, float d) {
    int r = __builtin_amdgcn_cvt_pk_fp8_f32(a, b, 0, false);   // bytes 0,1
    r = __builtin_amdgcn_cvt_pk_fp8_f32(c, d, r, true);        // bytes 2,3
    return r;
}
__device__ __forceinline__ unsigned char fp8_1(float a) {
    return (unsigned char)(__builtin_amdgcn_cvt_pk_fp8_f32(a, 0.f, 0, false) & 0xff);
}

// ---- prep: weights -> bf16 A-fragment tiles in d_ws, BIAS FOLDED at c==20 ----
// wAll = 16 tiles x [16 ch][32 c] bf16 (k:0..6, q:7..13, v:14..15).
// Row c=20 of each tile holds the bias (x fragment supplies 1.0 there).
__global__ void prep(const float* __restrict__ Wk, const float* __restrict__ bk,
                     const float* __restrict__ Wq, const float* __restrict__ bq,
                     const float* __restrict__ Wv, const float* __restrict__ bv,
                     short* __restrict__ wkT, short* __restrict__ wqT,
                     short* __restrict__ wvT)
{
    const int t = blockIdx.x * blockDim.x + threadIdx.x;
    if (t < 112 * 32) {
        const int n = t >> 5, c = t & 31;
        float vk = 0.f, vq = 0.f;
        if (n < KQ) {
            if (c < C)       { vk = Wk[c * KQ + n]; vq = Wq[c * KQ + n]; }
            else if (c == C) { vk = bk[n];          vq = bq[n]; }
        }
        wkT[t] = f2bf(vk);
        wqT[t] = f2bf(vq);
        if (t < 32 * 32) {
            const int n2 = t >> 5, c2 = t & 31;
            float vv = 0.f;
            if (n2 < C) {
                if (c2 < C)       vv = Wv[c2 * C + n2];
                else if (c2 == C) vv = bv[n2];
            }
            wvT[t] = f2bf(vv);
        }
    }
}

// One block per batch, 512 threads, 38.3 KB LDS -> 3 blocks/CU (75% occ).
// R8-known-good structure (launch_bounds(512,8), direct-store epilogue,
// 3 barriers) + two pure-data changes: bias folded into weight tiles, and
// weight fragments preloaded in batches of 4 so the proj loads pipeline
// within the 64-VGPR budget.
__global__ __launch_bounds__(NT, 8) void sa_fused(
    const float* __restrict__ x,
    const short* __restrict__ wAll,
    float* __restrict__ y)
{
    __shared__ __align__(16) unsigned char kp8[T * LDS8];   // k fp8 [i][d] -> later 64*P [i][j]
    __shared__ __align__(16) unsigned char q8 [T * LDS8];   // q fp8 [j][d]
    __shared__ __align__(16) unsigned char vT8[32 * LDS8];  // v^T fp8 [dd][pos] (rows 20..31 = 0)

    const int tid  = threadIdx.x;
    const int lane = tid & 63;
    const int w    = __builtin_amdgcn_readfirstlane(tid >> 6);
    const int quad = lane >> 4;
    const int l16  = lane & 15;
    const int b    = blockIdx.x;
    const float* xb = x + (size_t)b * (T * C);

    // ---- zero pad cols 112..127 of kp8/q8 (d-tail read by score K-loop) ----
    if (tid < T) {
        const uint2 z = {0u, 0u};
        *(uint2*)&kp8[tid * LDS8 + 112] = z;
        *(uint2*)&kp8[tid * LDS8 + 120] = z;
        *(uint2*)&q8 [tid * LDS8 + 112] = z;
        *(uint2*)&q8 [tid * LDS8 + 120] = z;
    }

    // ---- x fragment (built once): A[m=l16][k=quad*8+u] == B[k][n=l16];
    //      c pad 20->32, with c=20 element = 1.0 (bias row multiplier) ----
    bf16x8 xf;
    {
        const float* xr = xb + (w * 16 + l16) * C;
        uint32 p0 = 0, p1 = 0, p2 = 0, p3 = 0;
        if (quad < 2) {
            const float4 f0 = *(const float4*)(xr + quad * 8);
            const float4 f1 = *(const float4*)(xr + quad * 8 + 4);
            p0 = pk2(f0.x, f0.y); p1 = pk2(f0.z, f0.w);
            p2 = pk2(f1.x, f1.y); p3 = pk2(f1.z, f1.w);
        } else if (quad == 2) {
            const float4 f0 = *(const float4*)(xr + 16);
            p0 = pk2(f0.x, f0.y); p1 = pk2(f0.z, f0.w);
            p2 = pk2(1.f, 0.f);                       // c=20 -> 1.0 (bias row)
        }
        uint4 u4; u4.x = p0; u4.y = p1; u4.z = p2; u4.w = p3;
        xf = __builtin_bit_cast(bf16x8, u4);
    }

    // ---- projections (bf16 MFMA): wave w owns i-tile w. Weight fragments
    //      preloaded in batches of 4 (16 VGPRs) so loads pipeline. ----
    #pragma unroll
    for (int grp = 0; grp < 4; ++grp) {
        bf16x8 wfr[4];
        #pragma unroll
        for (int t = 0; t < 4; ++t)
            wfr[t] = *(const bf16x8*)(wAll + ((grp * 4 + t) * 16 + l16) * 32 + quad * 8);
        #pragma unroll
        for (int s = 0; s < 4; ++s) {
            const int tt = grp * 4 + s;
            const f32x4 cc = __builtin_amdgcn_mfma_f32_16x16x32_bf16(
                wfr[s], xf, (f32x4){0.f, 0.f, 0.f, 0.f}, 0, 0, 0);
            if (tt < 14) {                                        // k or q: ELU -> fp8 b32 write
                float e[4];
                #pragma unroll
                for (int r = 0; r < 4; ++r) {
                    const float z = cc[r];
                    e[r] = z > 0.f ? z : (__expf(z) - 1.f);
                }
                unsigned char* dst = (tt < 7)
                    ? &kp8[(w * 16 + l16) * LDS8 + tt * 16 + quad * 4]
                    : &q8 [(w * 16 + l16) * LDS8 + (tt - 7) * 16 + quad * 4];
                *(int*)dst = pkfp8x4(e[0], e[1], e[2], e[3]);
            } else {                                              // v: tanh -> vT scatter (b8)
                #pragma unroll
                for (int r = 0; r < 4; ++r) {
                    const float e2 = __expf(2.f * cc[r]);
                    vT8[((tt - 14) * 16 + quad * 4 + r) * LDS8 + w * 16 + l16]
                        = fp8_1(1.f - 2.f / (e2 + 1.f));
                }
            }
        }
    }
    __syncthreads();

    // ---- scores TRANSPOSED (fp8): S^T = q.k^T. A = q rows j (m-tile w), B = k (n=i). ----
    f32x4 acc[8];
    #pragma unroll
    for (int nt = 0; nt < 8; ++nt) acc[nt] = (f32x4){0.f, 0.f, 0.f, 0.f};
    #pragma unroll
    for (int ks = 0; ks < 4; ++ks) {
        const long a = *(const long*)&q8[(w * 16 + l16) * LDS8 + ks * 32 + quad * 8];
        #pragma unroll
        for (int nt = 0; nt < 8; ++nt) {
            const long bk8 = *(const long*)&kp8[(nt * 16 + l16) * LDS8 + ks * 32 + quad * 8];
            acc[nt] = __builtin_amdgcn_mfma_f32_16x16x32_fp8_fp8(a, bk8, acc[nt], 0, 0, 0);
        }
    }

    // ---- softmax over i (axis=1), in registers ----
    // Thread holds (j = w*16+quad*4+r, i = nt*16+l16). Sum over i = nt-sum + l16 butterfly.
    float ssum[4] = {0.f, 0.f, 0.f, 0.f};
    #pragma unroll
    for (int nt = 0; nt < 8; ++nt)
        #pragma unroll
        for (int r = 0; r < 4; ++r) {
            const float e = __expf(acc[nt][r] * SCALE);
            acc[nt][r] = e;
            ssum[r] += e;
        }
    #pragma unroll
    for (int r = 0; r < 4; ++r) {
        float s = ssum[r];
        s += __shfl_xor(s, 1); s += __shfl_xor(s, 2);
        s += __shfl_xor(s, 4); s += __shfl_xor(s, 8);
        ssum[r] = 64.f / s;                                       // 64*linv[j] (fp8 range lift)
    }
    __syncthreads();                                              // all score reads of kp8/q8 done

    // ---- write 64*P[i][j] fp8 (b32: 4 consecutive j per thread) over k ----
    #pragma unroll
    for (int nt = 0; nt < 8; ++nt) {
        *(int*)&kp8[(nt * 16 + l16) * LDS8 + w * 16 + quad * 4]
            = pkfp8x4(acc[nt][0] * ssum[0], acc[nt][1] * ssum[1],
                      acc[nt][2] * ssum[2], acc[nt][3] * ssum[3]);
    }
    __syncthreads();

    // ---- PV (fp8): A = 64P (m-tile w, K = j = 128), B = v^T (N = 32) ----
    f32x4 yacc[2];
    yacc[0] = (f32x4){0.f, 0.f, 0.f, 0.f};
    yacc[1] = (f32x4){0.f, 0.f, 0.f, 0.f};
    #pragma unroll
    for (int ks = 0; ks < 4; ++ks) {
        const long a = *(const long*)&kp8[(w * 16 + l16) * LDS8 + ks * 32 + quad * 8];
        #pragma unroll
        for (int nt = 0; nt < 2; ++nt) {
            const long bv8 = *(const long*)&vT8[(nt * 16 + l16) * LDS8 + ks * 32 + quad * 8];
            yacc[nt] = __builtin_amdgcn_mfma_f32_16x16x32_fp8_fp8(a, bv8, yacc[nt], 0, 0, 0);
        }
    }

    // ---- epilogue: y = PV/64 + x (direct stores, R8-known-good) ----
    {
        float* yb = y + (size_t)b * (T * C);
        const float inv64 = 1.f / 64.f;
        #pragma unroll
        for (int r = 0; r < 4; ++r) {
            const int row  = w * 16 + quad * 4 + r;
            const int base = row * C;
            yb[base + l16] = yacc[0][r] * inv64 + xb[base + l16];
            if (l16 < 4)
                yb[base + 16 + l16] = yacc[1][r] * inv64 + xb[base + 16 + l16];
        }
    }
}

extern "C" void kernel_launch(void* const* d_in, const int* in_sizes, int n_in,
                              void* d_out, int out_size, void* d_ws, size_t ws_size,
                              hipStream_t stream) {
    const float* x  = (const float*)d_in[0];
    const float* Wk = (const float*)d_in[1];
    const float* bk = (const float*)d_in[2];
    const float* Wq = (const float*)d_in[3];
    const float* bq = (const float*)d_in[4];
    const float* Wv = (const float*)d_in[5];
    const float* bv = (const float*)d_in[6];
    float* y = (float*)d_out;

    char* ws = (char*)d_ws;
    short* wkT = (short*)ws;                 // tiles 0..6   [112][32] bf16 (bias at c=20)
    short* wqT = (short*)(ws + 7168);        // tiles 7..13  [112][32] bf16
    short* wvT = (short*)(ws + 14336);       // tiles 14..15 [32][32]  bf16

    prep<<<14, 256, 0, stream>>>(Wk, bk, Wq, bq, Wv, bv, wkT, wqT, wvT);

    const int B = in_sizes[0] / (T * C);     // 4096
    sa_fused<<<B, NT, 0, stream>>>(x, (const short*)ws, y);
}